// Round 6
// baseline (140.242 us; speedup 1.0000x reference)
//
#include <hip/hip_runtime.h>

#define NB 4
#define NC 64
#define NH 256
#define NW 256
#define TH 32                  // output rows per block (4 waves x 8 rows)
#define SROWS (TH + 6)         // 38 staged input rows (incl. +/-3 halo)
#define LROW 264               // LDS row: 4 zero-pad | 256 data | 4 zero-pad

// ---------- phase 1: per-pixel g only (inv2 is re-derived in phase 2 with the
// identical op sequence -> bitwise-same results, half the ws traffic) ----------
__global__ __launch_bounds__(256)
void wprep(const float* __restrict__ persp,
           const float* __restrict__ alpha_p,
           const float* __restrict__ beta_p,
           const float* __restrict__ gamma_p,
           float* __restrict__ wg)
{
    const float alpha = alpha_p[0];
    const float beta  = beta_p[0];
    const float gamma = gamma_p[0];
    const int i = (blockIdx.x * 256 + threadIdx.x) * 4;
    const float4 p = *(const float4*)(persp + i);
    const float pa[4] = {p.x, p.y, p.z, p.w};
    float g[4];
    #pragma unroll
    for (int k = 0; k < 4; ++k) {
        const float z  = fmaf(beta, pa[k], gamma);
        const float sg = __builtin_amdgcn_rcpf(1.0f + __expf(-z));
        const float sigma = fmaxf(alpha * sg, 1e-4f);
        const float t  = 0.5f * __builtin_amdgcn_rcpf(sigma * sigma);
        g[k] = __expf(-t);
    }
    *(float4*)(wg + i) = make_float4(g[0], g[1], g[2], g[3]);
}

// ---------- phase 2: LDS stage + 7x10 register window, zero hot-loop globals ----------
// Register-budget ledger (hard-won):
//   (256,2): budget 256 -> AGPR-split, 2 w/SIMD, 44 us
//   (256,4): budget 128 -> SCRATCH SPILL (WRITE 65->331 MB), 150 us
//   (256,3): budget 168 -> no spill, 45 us. KEEP (256,3).
// Round-5 lesson: register shape doesn't move the needle; the ~70% stall was
// traced to per-iteration global ws loads (L3-latency, 1-iter prefetch).
// This round hoists ALL ws (g-plane only) into 32 regs before the barrier.
__global__ __launch_bounds__(256, 3)
void adaptive_gauss7(const float* __restrict__ x,
                     const float* __restrict__ wgp,
                     float* __restrict__ out)
{
    __shared__ float lds[SROWS * LROW];   // 40,128 B -> 4 blocks/CU max by LDS

    const int tid  = threadIdx.x;
    const int lane = tid & 63;
    const int wv   = tid >> 6;            // 4 waves x 8 rows = 32 rows
    const int c    = blockIdx.x;
    const int h0   = blockIdx.y * TH;
    const int b    = blockIdx.z;
    const int colbase = lane * 4;         // output cols colbase..colbase+3
    const int rg      = h0 + wv * 8;      // first output row of this wave

    const float* xc   = x   + (size_t)(b * NC + c) * NH * NW;
    float*       outp = out + (size_t)(b * NC + c) * NH * NW;
    const float* wrow = wgp + (size_t)b * NH * NW;

    // (1) issue ALL 8 rows' g loads NOW — latency hides under the DMA drain.
    float4 wsg[8];
    #pragma unroll
    for (int o = 0; o < 8; ++o)
        wsg[o] = *(const float4*)(wrow + (size_t)(rg + o) * NW + colbase);

    // (2) side pads: zero 4 floats at both ends of each staged row
    if (tid < SROWS) {
        *(float4*)&lds[tid * LROW]       = make_float4(0.f, 0.f, 0.f, 0.f);
        *(float4*)&lds[tid * LROW + 260] = make_float4(0.f, 0.f, 0.f, 0.f);
    }

    // (3) async stage: wave-interleaved rows, DMA straight to LDS
    for (int r = wv; r < SROWS; r += 4) {
        const int gr = h0 - 3 + r;                     // wave-uniform bound
        if ((unsigned)gr < NH) {
            __builtin_amdgcn_global_load_lds(
                (const __attribute__((address_space(1))) void*)(xc + (size_t)gr * NW + colbase),
                (__attribute__((address_space(3))) void*)&lds[r * LROW + 4],
                16, 0, 0);
        } else {
            *(float4*)&lds[r * LROW + 4 + colbase] = make_float4(0.f, 0.f, 0.f, 0.f);
        }
    }
    __syncthreads();

    // window: 7 rows x 10 cols = cols colbase-3 .. colbase+6 (only live taps).
    // tile row (wv*8 + o + j) lives in slot (o + j) % 7.
    float win[7][10];
    auto fill = [&](float (&dst)[10], int tr) {
        const float* rp = &lds[tr * LROW + colbase];  // cols colbase-4 .. +7
        const float4 a0 = *(const float4*)(rp);
        const float4 a1 = *(const float4*)(rp + 4);
        const float4 a2 = *(const float4*)(rp + 8);
        dst[0] = a0.y; dst[1] = a0.z; dst[2] = a0.w;          // cols -3..-1
        dst[3] = a1.x; dst[4] = a1.y; dst[5] = a1.z; dst[6] = a1.w;  // 0..3
        dst[7] = a2.x; dst[8] = a2.y; dst[9] = a2.z;          // 4..6
    };
    #pragma unroll
    for (int r = 0; r < 7; ++r)
        fill(win[r], wv * 8 + r);

    #pragma unroll
    for (int o = 0; o < 8; ++o) {
        // compute output row rg+o; pixel k taps window cols q = k .. k+6.
        // inv2 derived from g with wprep's exact op sequence (bitwise same).
        const float gk[4] = {wsg[o].x, wsg[o].y, wsg[o].z, wsg[o].w};
        float res[4];
        #pragma unroll
        for (int k = 0; k < 4; ++k) {
            const float g  = gk[k];
            const float g2 = g * g;
            const float p4 = g2 * g2;
            const float p9 = p4 * p4 * g;
            const float S  = fmaf(2.0f, (g + p4) + p9, 1.0f);
            const float inv  = __builtin_amdgcn_rcpf(S);
            const float inv2 = inv * inv;

            float rs[7];
            #pragma unroll
            for (int j = 0; j < 7; ++j) {
                const int s = (o + j) % 7;     // static after unroll
                rs[j] = fmaf(p9, win[s][k]     + win[s][k + 6],
                        fmaf(p4, win[s][k + 1] + win[s][k + 5],
                        fmaf(g,  win[s][k + 2] + win[s][k + 4],
                                 win[s][k + 3])));
            }
            const float acc = fmaf(p9, rs[0] + rs[6],
                              fmaf(p4, rs[1] + rs[5],
                              fmaf(g,  rs[2] + rs[4],
                                       rs[3])));
            res[k] = acc * inv2;
        }
        *(float4*)(outp + (size_t)(rg + o) * NW + colbase) =
            make_float4(res[0], res[1], res[2], res[3]);

        // refill the now-dead slot directly from LDS (use is 1 iteration away)
        if (o < 7)
            fill(win[o % 7], wv * 8 + o + 7);
    }
}

extern "C" void kernel_launch(void* const* d_in, const int* in_sizes, int n_in,
                              void* d_out, int out_size, void* d_ws, size_t ws_size,
                              hipStream_t stream) {
    const float* x     = (const float*)d_in[0];
    const float* persp = (const float*)d_in[1];
    const float* alpha = (const float*)d_in[2];
    const float* beta  = (const float*)d_in[3];
    const float* gamma = (const float*)d_in[4];
    float* outp        = (float*)d_out;
    float* wg          = (float*)d_ws;       // 4*256*256 floats = 1 MiB

    wprep<<<dim3((NB * NH * NW) / 1024), dim3(256), 0, stream>>>(persp, alpha, beta, gamma, wg);
    adaptive_gauss7<<<dim3(NC, NH / TH, NB), dim3(256), 0, stream>>>(x, wg, outp);
}

// Round 7
// 136.087 us; speedup vs baseline: 1.0305x; 1.0305x over previous
//
#include <hip/hip_runtime.h>

#define NB 4
#define NC 64
#define NH 256
#define NW 256
#define TH 32                  // output rows per block (4 waves x 8 rows)
#define SROWS (TH + 6)         // 38 staged input rows (incl. +/-3 halo)
#define LROW 256               // LDS row: no side pads — DPP zero-fill IS the pad

// ---------- phase 1: per-pixel g only (inv2 re-derived in phase 2, bitwise same) ----------
__global__ __launch_bounds__(256)
void wprep(const float* __restrict__ persp,
           const float* __restrict__ alpha_p,
           const float* __restrict__ beta_p,
           const float* __restrict__ gamma_p,
           float* __restrict__ wg)
{
    const float alpha = alpha_p[0];
    const float beta  = beta_p[0];
    const float gamma = gamma_p[0];
    const int i = (blockIdx.x * 256 + threadIdx.x) * 4;
    const float4 p = *(const float4*)(persp + i);
    const float pa[4] = {p.x, p.y, p.z, p.w};
    float g[4];
    #pragma unroll
    for (int k = 0; k < 4; ++k) {
        const float z  = fmaf(beta, pa[k], gamma);
        const float sg = __builtin_amdgcn_rcpf(1.0f + __expf(-z));
        const float sigma = fmaxf(alpha * sg, 1e-4f);
        const float t  = 0.5f * __builtin_amdgcn_rcpf(sigma * sigma);
        g[k] = __expf(-t);
    }
    *(float4*)(wg + i) = make_float4(g[0], g[1], g[2], g[3]);
}

// lane i <- lane i-1 (data shifts toward higher lanes); lane 0 gets 0.0f.
// Wave spans the full 256-px image row, so the zero-fill IS the left pad.
__device__ __forceinline__ float dpp_shr1(float v) {
    return __int_as_float(__builtin_amdgcn_update_dpp(
        0, __float_as_int(v), 0x138 /*WAVE_SHR1*/, 0xf, 0xf, true));
}
// lane i <- lane i+1; lane 63 gets 0.0f (right pad).
__device__ __forceinline__ float dpp_shl1(float v) {
    return __int_as_float(__builtin_amdgcn_update_dpp(
        0, __float_as_int(v), 0x130 /*WAVE_SHL1*/, 0xf, 0xf, true));
}

// ---------- phase 2: LDS stage + 7x4 register window + DPP halo columns ----------
// Ledger: (256,2) AGPR-split 44us | (256,4) SPILL 150us | (256,3) no-spill 45us.
// Round-6 lesson: the invariant ~45us was LDS-read-pipe bound: 45 b128/wave at
// ~36 cyc each (SQ_LDS_BANK_CONFLICT ~ 24 extra cyc/read) = ~20us/CU of LDS.
// This round: 1 b128 per row (14/wave); the 6 halo cols come from neighbor
// lanes via v_mov_dpp wave_shr/shl (VALU pipe, zero-fill = image pad).
__global__ __launch_bounds__(256, 3)
void adaptive_gauss7(const float* __restrict__ x,
                     const float* __restrict__ wgp,
                     float* __restrict__ out)
{
    __shared__ float lds[SROWS * LROW];   // 38,912 B -> 4 blocks/CU by LDS

    const int tid  = threadIdx.x;
    const int lane = tid & 63;
    const int wv   = tid >> 6;            // 4 waves x 8 rows = 32 rows
    const int c    = blockIdx.x;
    const int h0   = blockIdx.y * TH;
    const int b    = blockIdx.z;
    const int colbase = lane * 4;         // output cols colbase..colbase+3
    const int rg      = h0 + wv * 8;      // first output row of this wave

    const float* xc   = x   + (size_t)(b * NC + c) * NH * NW;
    float*       outp = out + (size_t)(b * NC + c) * NH * NW;
    const float* wrow = wgp + (size_t)b * NH * NW;

    // (1) all 8 rows' g hoisted now — latency hides under the DMA drain
    float4 wsg[8];
    #pragma unroll
    for (int o = 0; o < 8; ++o)
        wsg[o] = *(const float4*)(wrow + (size_t)(rg + o) * NW + colbase);

    // (2) async stage: wave-interleaved rows, DMA straight to LDS (no pads)
    for (int r = wv; r < SROWS; r += 4) {
        const int gr = h0 - 3 + r;                     // wave-uniform bound
        if ((unsigned)gr < NH) {
            __builtin_amdgcn_global_load_lds(
                (const __attribute__((address_space(1))) void*)(xc + (size_t)gr * NW + colbase),
                (__attribute__((address_space(3))) void*)&lds[r * LROW],
                16, 0, 0);
        } else {
            *(float4*)&lds[r * LROW + colbase] = make_float4(0.f, 0.f, 0.f, 0.f);
        }
    }
    __syncthreads();

    // (3) window: 7 rows x 4 cols (own columns only). Row (wv*8+o+j) in slot (o+j)%7.
    float win[7][4];
    #pragma unroll
    for (int r = 0; r < 7; ++r) {
        const float4 a = *(const float4*)&lds[(wv * 8 + r) * LROW + colbase];
        win[r][0] = a.x; win[r][1] = a.y; win[r][2] = a.z; win[r][3] = a.w;
    }

    #pragma unroll
    for (int o = 0; o < 8; ++o) {
        // per-pixel weight powers (inv2 derived with wprep's exact op sequence)
        const float gk[4] = {wsg[o].x, wsg[o].y, wsg[o].z, wsg[o].w};
        float g[4], p4[4], p9[4], inv2[4];
        #pragma unroll
        for (int k = 0; k < 4; ++k) {
            g[k] = gk[k];
            const float g2 = g[k] * g[k];
            p4[k] = g2 * g2;
            p9[k] = p4[k] * p4[k] * g[k];
            const float S  = fmaf(2.0f, (g[k] + p4[k]) + p9[k], 1.0f);
            const float iv = __builtin_amdgcn_rcpf(S);
            inv2[k] = iv * iv;
        }

        // horizontal pass per row: 1 stored b128 + 6 DPP halos -> 10-wide window
        float s0[4], s1[4], s2[4], s3[4];   // pair-sum slots per pixel
        #pragma unroll
        for (int j = 0; j < 7; ++j) {
            const int s = (o + j) % 7;      // static after unroll
            const float w[10] = {
                dpp_shr1(win[s][1]),        // col -3
                dpp_shr1(win[s][2]),        // col -2
                dpp_shr1(win[s][3]),        // col -1
                win[s][0], win[s][1], win[s][2], win[s][3],
                dpp_shl1(win[s][0]),        // col +4
                dpp_shl1(win[s][1]),        // col +5
                dpp_shl1(win[s][2])         // col +6
            };
            #pragma unroll
            for (int k = 0; k < 4; ++k) {
                const float rs = fmaf(p9[k], w[k]     + w[k + 6],
                                 fmaf(p4[k], w[k + 1] + w[k + 5],
                                 fmaf(g[k],  w[k + 2] + w[k + 4],
                                             w[k + 3])));
                if      (j == 0) s0[k] = rs;
                else if (j == 1) s1[k] = rs;
                else if (j == 2) s2[k] = rs;
                else if (j == 3) s3[k] = rs;
                else if (j == 4) s2[k] = s2[k] + rs;
                else if (j == 5) s1[k] = s1[k] + rs;
                else             s0[k] = s0[k] + rs;
            }
        }

        // vertical combine — same association as rounds 0-6
        float res[4];
        #pragma unroll
        for (int k = 0; k < 4; ++k) {
            res[k] = fmaf(p9[k], s0[k],
                     fmaf(p4[k], s1[k],
                     fmaf(g[k],  s2[k], s3[k]))) * inv2[k];
        }
        *(float4*)(outp + (size_t)(rg + o) * NW + colbase) =
            make_float4(res[0], res[1], res[2], res[3]);

        // refill the dead slot: ONE b128 (own 4 columns only)
        if (o < 7) {
            const float4 a = *(const float4*)&lds[(wv * 8 + o + 7) * LROW + colbase];
            win[o % 7][0] = a.x; win[o % 7][1] = a.y;
            win[o % 7][2] = a.z; win[o % 7][3] = a.w;
        }
    }
}

extern "C" void kernel_launch(void* const* d_in, const int* in_sizes, int n_in,
                              void* d_out, int out_size, void* d_ws, size_t ws_size,
                              hipStream_t stream) {
    const float* x     = (const float*)d_in[0];
    const float* persp = (const float*)d_in[1];
    const float* alpha = (const float*)d_in[2];
    const float* beta  = (const float*)d_in[3];
    const float* gamma = (const float*)d_in[4];
    float* outp        = (float*)d_out;
    float* wg          = (float*)d_ws;       // 4*256*256 floats = 1 MiB

    wprep<<<dim3((NB * NH * NW) / 1024), dim3(256), 0, stream>>>(persp, alpha, beta, gamma, wg);
    adaptive_gauss7<<<dim3(NC, NH / TH, NB), dim3(256), 0, stream>>>(x, wg, outp);
}